// Round 3
// baseline (396.814 us; speedup 1.0000x reference)
//
#include <hip/hip_runtime.h>
#include <hip/hip_bf16.h>

typedef __hip_bfloat16 bf16;
typedef __attribute__((ext_vector_type(8))) short bf16x8v;  // 8 bf16 = 4 VGPRs
typedef __attribute__((ext_vector_type(4))) float f32x4v;   // MFMA accumulator

// ---------- helpers -----------------------------------------------------------
__device__ __forceinline__ float bfbits2f(unsigned short h) {
    union { unsigned int u; float f; } v; v.u = ((unsigned int)h) << 16; return v.f;
}
__device__ __forceinline__ unsigned short f2bfbits(float f) {
    bf16 h = __float2bfloat16(f);
    unsigned short s;
    __builtin_memcpy(&s, &h, 2);
    return s;
}
__device__ __forceinline__ float load1_any(const void* p, long idx, bool f32) {
    if (f32) return ((const float*)p)[idx];
    return bfbits2f(((const unsigned short*)p)[idx]);
}
__device__ __forceinline__ float4 loadbf4(const bf16* p) {
    ushort4 u = *reinterpret_cast<const ushort4*>(p);
    return make_float4(bfbits2f(u.x), bfbits2f(u.y), bfbits2f(u.z), bfbits2f(u.w));
}
__device__ __forceinline__ void store_bf4(bf16* p, float a, float b, float c, float d) {
    ushort4 o;
    o.x = f2bfbits(a); o.y = f2bfbits(b); o.z = f2bfbits(c); o.w = f2bfbits(d);
    *reinterpret_cast<ushort4*>(p) = o;
}
// async global->LDS, 16B per lane; LDS dest = wave-uniform base + lane*16
__device__ __forceinline__ void gl16(const void* g, void* l) {
    __builtin_amdgcn_global_load_lds(
        (const __attribute__((address_space(1))) unsigned int*)g,
        (__attribute__((address_space(3))) unsigned int*)l, 16, 0, 0);
}

// ---------- input dtype detection (flag=1: read raw inputs as fp32) -----------
__global__ __launch_bounds__(1024)
void detect_kernel(const unsigned short* __restrict__ x, int* __restrict__ flag) {
    const int tid = threadIdx.x;
    int zc = 0, hc = 0;
    const uint4* xv = (const uint4*)x;
#pragma unroll
    for (int p = 0; p < 16; ++p) {
        uint4 v = xv[p * 1024 + tid];
        unsigned s0 = v.x & 0xFFFFu, s1 = v.y & 0xFFFFu;
        unsigned s2 = v.z & 0xFFFFu, s3 = v.w & 0xFFFFu;
        zc += (int)(s0 == 0) + (int)(s1 == 0) + (int)(s2 == 0) + (int)(s3 == 0);
        hc += (int)(((s0 >> 7) & 0xFFu) >= 0x90u) + (int)(((s1 >> 7) & 0xFFu) >= 0x90u)
            + (int)(((s2 >> 7) & 0xFFu) >= 0x90u) + (int)(((s3 >> 7) & 0xFFu) >= 0x90u);
    }
#pragma unroll
    for (int off = 32; off > 0; off >>= 1) {
        zc += __shfl_down(zc, off);
        hc += __shfl_down(hc, off);
    }
    __shared__ int rz[16], rh[16];
    if ((tid & 63) == 0) { rz[tid >> 6] = zc; rh[tid >> 6] = hc; }
    __syncthreads();
    if (tid == 0) {
        int Z = 0, H = 0;
#pragma unroll
        for (int i = 0; i < 16; ++i) { Z += rz[i]; H += rh[i]; }
        *flag = (Z > 60000 || H > 256) ? 1 : 0;
    }
}

__global__ void diag_kernel(float* __restrict__ out, float val) {
    if (threadIdx.x == 0) out[0] = val;
}

// ---------- fused weight convert: all 6 weight tensors in one dispatch --------
__global__ __launch_bounds__(256)
void convert6_kernel(const void* __restrict__ s0, const void* __restrict__ s1,
                     const void* __restrict__ s2, const void* __restrict__ s3,
                     const void* __restrict__ s4, const void* __restrict__ s5,
                     bf16* __restrict__ dst, const int* __restrict__ dflag) {
    const bool f32 = (*dflag != 0);
    for (long i = (long)blockIdx.x * 256 + threadIdx.x; i < 4456448;
         i += (long)gridDim.x * 256) {
        const void* s; long o;
        if (i < 131072)       { s = s0; o = i; }
        else if (i < 196608)  { s = s1; o = i - 131072; }
        else if (i < 262144)  { s = s2; o = i - 196608; }
        else if (i < 2359296) { s = s3; o = i - 262144; }
        else if (i < 3407872) { s = s4; o = i - 2359296; }
        else                  { s = s5; o = i - 3407872; }
        dst[i] = __float2bfloat16(load1_any(s, o, f32));
    }
}

// ---------- transpose+convert: x[bg][256][1024] raw -> xT[z][1024][256] bf16 --
__global__ __launch_bounds__(256)
void xpose_conv_kernel(const void* __restrict__ x1, const void* __restrict__ x2,
                       bf16* __restrict__ dst, int bofs, int zsplit,
                       const int* __restrict__ dflag) {
    const bool f32 = (*dflag != 0);
    __shared__ float t[64][65];
    const int ch0 = blockIdx.y * 64, n0 = blockIdx.x * 64, z = blockIdx.z;
    const bool hiz = (z >= zsplit);
    const int zl = hiz ? z - zsplit : z;
    const void* x = hiz ? x2 : x1;
    const long sb = (long)(zl + bofs) * 262144, db = (long)z * 262144;
    const int tid = threadIdx.x;
#pragma unroll
    for (int p = 0; p < 16; ++p) {
        int e = tid + p * 256; int sch = e >> 6, sn = e & 63;
        t[sch][sn] = load1_any(x, sb + (long)(ch0 + sch) * 1024 + n0 + sn, f32);
    }
    __syncthreads();
#pragma unroll
    for (int p = 0; p < 16; ++p) {
        int e = tid + p * 256; int dn = e >> 6, dch = e & 63;
        dst[db + (long)(n0 + dn) * 256 + ch0 + dch] = __float2bfloat16(t[dch][dn]);
    }
}

// ---------- column softmax (no normalize): X[j][n] -> exp(X - max_j), invS[n] --
// softmax runs over j (rows) for each column n. Block: 64 cols x 4 row-quarters.
// Pass 1: column max. Pass 2 (L2-hot re-read): write exp(v-M) in place, sum -> invS.
__global__ __launch_bounds__(256)
void smnorm_kernel(bf16* __restrict__ X, float* __restrict__ invS) {
    const int tid = threadIdx.x, c = tid & 63, jp = tid >> 6;
    const int n0 = blockIdx.x * 64;
    const long zb = (long)blockIdx.y * 1048576;
    bf16* Xp = X + zb + n0 + c;
    float m = -3.4e38f;
#pragma unroll 4
    for (int it = 0; it < 256; ++it) {
        float v = bfbits2f(((const unsigned short*)Xp)[(long)(jp * 256 + it) * 1024]);
        m = fmaxf(m, v);
    }
    __shared__ float sh[4][64];
    sh[jp][c] = m;
    __syncthreads();
    const float M = fmaxf(fmaxf(sh[0][c], sh[1][c]), fmaxf(sh[2][c], sh[3][c]));
    __syncthreads();
    float s = 0.f;
#pragma unroll 4
    for (int it = 0; it < 256; ++it) {
        long off = (long)(jp * 256 + it) * 1024;
        float v = bfbits2f(((const unsigned short*)Xp)[off]);
        float e = __expf(v - M);
        ((unsigned short*)Xp)[off] = f2bfbits(e);
        s += e;
    }
    __syncthreads();
    sh[jp][c] = s;
    __syncthreads();
    if (jp == 0)
        invS[(long)blockIdx.y * 1024 + n0 + c] =
            1.0f / (sh[0][c] + sh[1][c] + sh[2][c] + sh[3][c]);
}

// ---------- unified NT MFMA GEMM, depth-5 counted-vmcnt pipeline --------------
// D[z][m][n] = sum_k A[z][m][k] * B[z][n][k]   (both operands k-contiguous)
// 128x128 tile / block (4 waves, each 64x64 via 4x4 grid of 16x16x32 MFMA).
// 5 LDS buffers; steady state keeps 3 stages (12 gl16) in flight beyond current:
//   wait vmcnt(4*min(3,rem)) -> barrier -> ds_read -> lgkmcnt(0) -> barrier ->
//   stage(t+4) -> MFMA
// z-split: z<zsplit uses side-1 params, else side-2 (zl=z-zsplit); swapXY swaps
// the block-grid meaning for side-2 (merged dispatches with transposed shapes).
// EPI: 0 plain | 1 +bias[row] | 2 *scale+bias[row] | 3 +res fp32 out
//      4 (v+bias[row])*colscale[col]   (colscale = fp32 via res ptr, stride rBatch)
template <int EPI>
__global__ __launch_bounds__(256)
void mfma_nt(const bf16* __restrict__ A1, const bf16* __restrict__ A2,
             long aB1, long aB2, int ldA1, int ldA2,
             const bf16* __restrict__ B1, const bf16* __restrict__ B2,
             long bB1, long bB2, int ldB1, int ldB2,
             int ksplit, long kOff2,
             void* __restrict__ out1, void* __restrict__ out2,
             long oB1, long oB2, int ldO1, int ldO2,
             int K, float scale,
             const void* __restrict__ bias1, const void* __restrict__ bias2,
             const void* __restrict__ res1, const void* __restrict__ res2,
             long rBatch, int bofs, int zsplit, int swapXY,
             const int* __restrict__ dflag) {
    __shared__ short As[5][4096];   // [buf][128 rows x 32 shorts]  8KB each
    __shared__ short Bs[5][4096];
    const int tid  = threadIdx.x;
    const int lane = tid & 63, wave = tid >> 6;
    const int quad = lane >> 4, lrow = lane & 15;
    const int wm = (wave >> 1) * 64, wn = (wave & 1) * 64;
    const int z  = blockIdx.z;
    const bool hiz = (z >= zsplit);
    const int zl = hiz ? z - zsplit : z;
    const bool sw = hiz && swapXY;
    const int n0 = (sw ? blockIdx.y : blockIdx.x) * 128;
    const int m0 = (sw ? blockIdx.x : blockIdx.y) * 128;
    const int ldA = hiz ? ldA2 : ldA1, ldB = hiz ? ldB2 : ldB1;
    const int ldO = hiz ? ldO2 : ldO1;
    const int srow = tid >> 2, sseg = tid & 3;
    const int sl = sseg ^ ((srow >> 1) & 3);        // staging: swizzled logical seg
    const int xq = quad ^ ((lrow >> 1) & 3);        // read: physical seg for my quad

    const bf16* Ab = (hiz ? A2 : A1) + (long)zl * (hiz ? aB2 : aB1);
    const bf16* Bb = (hiz ? B2 : B1) + (long)zl * (hiz ? bB2 : bB1);

    auto stage = [&](int buf, int k0) {
        const bf16* asrc = Ab + (long)k0;
        const bf16* bsrc = Bb + ((k0 < ksplit) ? (long)k0 : (long)(k0 - ksplit) + kOff2);
        const bf16* ga0 = asrc + (long)(m0 + srow) * ldA + sl * 8;
        const bf16* ga1 = asrc + (long)(m0 + 64 + srow) * ldA + sl * 8;
        const bf16* gb0 = bsrc + (long)(n0 + srow) * ldB + sl * 8;
        const bf16* gb1 = bsrc + (long)(n0 + 64 + srow) * ldB + sl * 8;
        short* la = &As[buf][wave * 512];
        short* lb = &Bs[buf][wave * 512];
        gl16(ga0, la);
        gl16(ga1, la + 2048);
        gl16(gb0, lb);
        gl16(gb1, lb + 2048);
    };

    f32x4v acc[4][4] = {};
    const int nt = K >> 5;
    stage(0, 0);
    if (nt > 1) stage(1, 32);
    if (nt > 2) stage(2, 64);
    if (nt > 3) stage(3, 96);

    int cur = 0;
    for (int t = 0; t < nt; ++t) {
        const int rem = nt - 1 - t;
        if (rem >= 3)      asm volatile("s_waitcnt vmcnt(12)" ::: "memory");
        else if (rem == 2) asm volatile("s_waitcnt vmcnt(8)" ::: "memory");
        else if (rem == 1) asm volatile("s_waitcnt vmcnt(4)" ::: "memory");
        else               asm volatile("s_waitcnt vmcnt(0)" ::: "memory");
        __builtin_amdgcn_s_barrier();            // all waves' tile-t loads landed
        __builtin_amdgcn_sched_barrier(0);
        bf16x8v bfr[4], afr[4];
#pragma unroll
        for (int j = 0; j < 4; ++j)
            bfr[j] = *(const bf16x8v*)&Bs[cur][(wn + j * 16 + lrow) * 32 + xq * 8];
#pragma unroll
        for (int i = 0; i < 4; ++i)
            afr[i] = *(const bf16x8v*)&As[cur][(wm + i * 16 + lrow) * 32 + xq * 8];
        asm volatile("s_waitcnt lgkmcnt(0)" ::: "memory");
        __builtin_amdgcn_sched_barrier(0);       // rule 18: MFMA can't hoist above
        __builtin_amdgcn_s_barrier();            // all waves done reading buf[cur]
        __builtin_amdgcn_sched_barrier(0);       // keep stage below the barrier
        if (t + 4 < nt) {
            int nb = cur + 4; if (nb >= 5) nb -= 5;
            stage(nb, (t + 4) << 5);
        }
#pragma unroll
        for (int i = 0; i < 4; ++i)
#pragma unroll
            for (int j = 0; j < 4; ++j)
                acc[i][j] = __builtin_amdgcn_mfma_f32_16x16x32_bf16(afr[i], bfr[j], acc[i][j], 0, 0, 0);
        cur = (cur == 4) ? 0 : cur + 1;
    }

    const bool f32 = (*dflag != 0);
    const void* bias = hiz ? bias2 : bias1;
    if (EPI != 3) {
        bf16* O = (bf16*)(hiz ? out2 : out1) + (long)zl * (hiz ? oB2 : oB1);
        const float* csp = (EPI == 4)
            ? (const float*)(hiz ? res2 : res1) + (long)zl * rBatch : nullptr;
#pragma unroll
        for (int i = 0; i < 4; ++i) {
            int row0 = m0 + wm + i * 16 + quad * 4;
            float rb[4] = {0.f, 0.f, 0.f, 0.f};
            if (EPI == 1 || EPI == 2 || EPI == 4) {
#pragma unroll
                for (int r = 0; r < 4; ++r) rb[r] = load1_any(bias, row0 + r, f32);
            }
#pragma unroll
            for (int j = 0; j < 4; ++j) {
                int col = n0 + wn + j * 16 + lrow;
                float cs = (EPI == 4) ? csp[col] : 1.0f;
#pragma unroll
                for (int r = 0; r < 4; ++r) {
                    float vv = acc[i][j][r];
                    if (EPI == 1) vv += rb[r];
                    if (EPI == 2) vv = vv * scale + rb[r];
                    if (EPI == 4) vv = (vv + rb[r]) * cs;
                    O[(long)(row0 + r) * ldO + col] = __float2bfloat16(vv);
                }
            }
        }
    } else {
        float* O = (float*)(hiz ? out2 : out1);
        const void* res = hiz ? res2 : res1;
        const long ob  = (long)(zl + bofs) * (hiz ? oB2 : oB1);
        const long rbb = (long)(zl + bofs) * rBatch;
#pragma unroll
        for (int i = 0; i < 4; ++i) {
            int row0 = m0 + wm + i * 16 + quad * 4;
#pragma unroll
            for (int j = 0; j < 4; ++j) {
                int col = n0 + wn + j * 16 + lrow;
#pragma unroll
                for (int r = 0; r < 4; ++r) {
                    float rv = load1_any(res, rbb + (long)(row0 + r) * ldO + col, f32);
                    O[ob + (long)(row0 + r) * ldO + col] = acc[i][j][r] + rv;
                }
            }
        }
    }
}

// ---------- LayerNorm over last dim (1024), bf16 in-place ---------------------
__global__ __launch_bounds__(256)
void layernorm_kernel(bf16* __restrict__ x, const void* __restrict__ g,
                      const void* __restrict__ beta, const int* __restrict__ dflag) {
    const bool f32 = (*dflag != 0);
    bf16* p = x + (long)blockIdx.x * 1024;
    const int tid = threadIdx.x;
    float4 v = loadbf4(p + tid * 4);
    float s  = v.x + v.y + v.z + v.w;
    float ss = v.x * v.x + v.y * v.y + v.z * v.z + v.w * v.w;
#pragma unroll
    for (int off = 32; off > 0; off >>= 1) {
        s  += __shfl_down(s, off);
        ss += __shfl_down(ss, off);
    }
    __shared__ float sh[8];
    __shared__ float sh_mu, sh_rs;
    if ((tid & 63) == 0) { sh[tid >> 6] = s; sh[4 + (tid >> 6)] = ss; }
    __syncthreads();
    if (tid == 0) {
        float S  = sh[0] + sh[1] + sh[2] + sh[3];
        float SS = sh[4] + sh[5] + sh[6] + sh[7];
        float mu = S * (1.0f / 1024.0f);
        float var = SS * (1.0f / 1024.0f) - mu * mu;
        sh_mu = mu;
        sh_rs = rsqrtf(fmaxf(var, 0.0f) + 1e-5f);
    }
    __syncthreads();
    float mu = sh_mu, rs = sh_rs;
    float gx = load1_any(g, tid * 4 + 0, f32), gy = load1_any(g, tid * 4 + 1, f32);
    float gz = load1_any(g, tid * 4 + 2, f32), gw = load1_any(g, tid * 4 + 3, f32);
    float bx = load1_any(beta, tid * 4 + 0, f32), by = load1_any(beta, tid * 4 + 1, f32);
    float bz = load1_any(beta, tid * 4 + 2, f32), bw = load1_any(beta, tid * 4 + 3, f32);
    store_bf4(p + tid * 4,
              (v.x - mu) * rs * gx + bx, (v.y - mu) * rs * gy + by,
              (v.z - mu) * rs * gz + bz, (v.w - mu) * rs * gw + bw);
}

// ---------- host ---------------------------------------------------------------
extern "C" void kernel_launch(void* const* d_in, const int* in_sizes, int n_in,
                              void* d_out, int out_size, void* d_ws, size_t ws_size,
                              hipStream_t stream) {
    const void* x_spa  = d_in[0];
    const void* x_freq = d_in[1];
    const void* w_cdc  = d_in[2];
    const void* b_cdc  = d_in[3];
    const void* w_sv   = d_in[4];
    const void* b_sv   = d_in[5];
    const void* w_fv   = d_in[6];
    const void* b_fv   = d_in[7];
    const void* ln_w   = d_in[8];
    const void* ln_b   = d_in[9];
    const void* w_qk   = d_in[10];
    const void* w_spa  = d_in[11];
    const void* b_spa  = d_in[12];
    const void* w_frq  = d_in[13];
    const void* b_frq  = d_in[14];
    float* out = (float*)d_out;          // fp32 output

    const int B = 16, C = 256;
    const long XB = 262144;              // [256][1024] or [1024][256] tiles
    const long PB = 1048576;             // [1024][1024]

    // ws: 4KB header | bf16 weights (4,456,448 elems) | G * per-batch
    int*  dflag = (int*)d_ws;
    bf16* wb    = (bf16*)((char*)d_ws + 4096);
    bf16* w_cdc_b = wb;                       // 131072  (256 x 512)
    bf16* w_sv_b  = w_cdc_b + 131072;         // 65536   (256 x 256)
    bf16* w_fv_b  = w_sv_b  + 65536;          // 65536
    bf16* w_qk_b  = w_fv_b  + 65536;          // 2097152 (2048 x 1024)
    bf16* w_spa_b = w_qk_b  + 2097152;        // 1048576 (1024 x 1024)
    bf16* w_frq_b = w_spa_b + 1048576;        // 1048576
    bf16* pb      = w_frq_b + 1048576;

    const size_t fixedB = 4096 + 4456448ull * 2;
    const size_t perB   = 8921088ull;         // 9*XB*2 + 2*PB*2 + 2*1024*4 bytes
    size_t avail = (ws_size > fixedB) ? (ws_size - fixedB) : 0;
    long gmax = (long)(avail / perB);
    const bool wsOK = (gmax >= 1);
    int G = wsOK ? (int)(gmax > 16 ? 16 : gmax) : 1;

    bf16* xT    = pb;                     // [2z][1024][256]  (spa: z<g, frq: z>=g)
    bf16* xln   = xT   + 2L * G * XB;     // [z][256][1024]
    bf16* kb    = xln  + (long)G * XB;    // [z][256][1024]
    bf16* qT    = kb   + (long)G * XB;    // [z][1024][256]
    bf16* TT    = qT   + (long)G * XB;    // [2z][1024][256]
    bf16* vb    = TT   + 2L * G * XB;     // [2z][256][1024]
    bf16* attpT = vb   + 2L * G * XB;     // [2z][1024][1024]  scores^T -> E
    float* invS = (float*)(attpT + 2L * G * PB);  // [2z][1024]

    dim3 blk(256);
    detect_kernel<<<dim3(1), dim3(1024), 0, stream>>>((const unsigned short*)x_spa, dflag);

    if (!wsOK) {
        float mb = (float)(ws_size >> 20);
        diag_kernel<<<dim3(1), dim3(64), 0, stream>>>(out, 1000.0f * (mb + 1.0f));
        return;
    }

    // all weights -> bf16 in one dispatch
    convert6_kernel<<<dim3(4352), blk, 0, stream>>>(w_cdc, w_sv, w_fv, w_qk, w_spa, w_frq,
                                                    wb, dflag);

    for (int b0 = 0; b0 < B; b0 += G) {
        int g = (B - b0 < G) ? (B - b0) : G;

        // x_spa/x_freq -> xT[2g] (bf16, [n][ch])
        xpose_conv_kernel<<<dim3(16, 4, 2 * g), blk, 0, stream>>>(
            x_spa, x_freq, xT, b0, g, dflag);

        // xln = w_cdc @ cat(x_spa, x_freq)  (rowbias, K split at 256)
        mfma_nt<1><<<dim3(8, 2, g), blk, 0, stream>>>(
            w_cdc_b, w_cdc_b, 0, 0, 512, 512,
            xT, xT, XB, XB, 256, 256, 256, (long)g * XB,
            xln, xln, XB, XB, 1024, 1024,
            512, 1.0f, b_cdc, b_cdc, nullptr, nullptr, 0, 0, g, 0, dflag);
        layernorm_kernel<<<dim3(g * C), blk, 0, stream>>>(xln, ln_w, ln_b, dflag);

        // merged: lo z -> kb[c][m] = xln . w_qk_hi ; hi z -> qT[n][c] = w_qk_lo . xln
        mfma_nt<0><<<dim3(8, 2, 2 * g), blk, 0, stream>>>(
            xln, w_qk_b, XB, 0, 1024, 1024,
            w_qk_b + 1048576, xln, 0, XB, 1024, 1024, 1024, 0,
            kb, qT, XB, XB, 1024, 256,
            1024, 1.0f, nullptr, nullptr, nullptr, nullptr, 0, 0, g, 1, dflag);

        // TT (both): TT[z][j][c] = w_{spa,frq} @ k^T
        mfma_nt<0><<<dim3(2, 8, 2 * g), blk, 0, stream>>>(
            w_spa_b, w_frq_b, 0, 0, 1024, 1024,
            kb, kb, XB, XB, 1024, 1024, 1024, 0,
            TT, TT + (long)g * XB, XB, XB, 256, 256,
            1024, 1.0f, nullptr, nullptr, nullptr, nullptr, 0, 0, g, 0, dflag);

        // attp transposed (both): attpT[z][j][n] = scale * (TT[j].qT[n]) + bias[j]
        mfma_nt<2><<<dim3(8, 8, 2 * g), blk, 0, stream>>>(
            TT, TT + (long)g * XB, XB, XB, 256, 256,
            qT, qT, XB, XB, 256, 256, 256, 0,
            attpT, attpT + (long)g * PB, PB, PB, 1024, 1024,
            256, 0.03125f, b_spa, b_frq, nullptr, nullptr, 0, 0, g, 0, dflag);

        // column softmax: attpT <- exp(attpT - colmax), invS[n] = 1/colsum
        smnorm_kernel<<<dim3(16, 2 * g), blk, 0, stream>>>(attpT, invS);

        // v (both): vb[z][c][n] = (w_{s,f}v . x + b) * invS[n]
        mfma_nt<4><<<dim3(8, 2, 2 * g), blk, 0, stream>>>(
            w_sv_b, w_fv_b, 0, 0, 256, 256,
            xT, xT + (long)g * XB, XB, XB, 256, 256, 256, 0,
            vb, vb + (long)g * XB, XB, XB, 1024, 1024,
            256, 1.0f, b_sv, b_fv, invS, invS + (long)g * 1024, 1024, 0, g, 0, dflag);

        // out (both): out = v' @ E^T + x   (fp32 out)
        mfma_nt<3><<<dim3(8, 2, 2 * g), blk, 0, stream>>>(
            vb, vb + (long)g * XB, XB, XB, 1024, 1024,
            attpT, attpT + (long)g * PB, PB, PB, 1024, 1024, 1024, 0,
            out, out + 4194304, XB, XB, 1024, 1024,
            1024, 1.0f, nullptr, nullptr, x_spa, x_freq, XB, b0, g, 0, dflag);
    }
}

// Round 4
// 346.536 us; speedup vs baseline: 1.1451x; 1.1451x over previous
//
#include <hip/hip_runtime.h>
#include <hip/hip_bf16.h>

typedef __hip_bfloat16 bf16;
typedef __attribute__((ext_vector_type(8))) short bf16x8v;  // 8 bf16 = 4 VGPRs
typedef __attribute__((ext_vector_type(4))) float f32x4v;   // MFMA accumulator

// ---------- helpers -----------------------------------------------------------
__device__ __forceinline__ float bfbits2f(unsigned short h) {
    union { unsigned int u; float f; } v; v.u = ((unsigned int)h) << 16; return v.f;
}
__device__ __forceinline__ unsigned short f2bfbits(float f) {
    bf16 h = __float2bfloat16(f);
    unsigned short s;
    __builtin_memcpy(&s, &h, 2);
    return s;
}
__device__ __forceinline__ float load1_any(const void* p, long idx, bool f32) {
    if (f32) return ((const float*)p)[idx];
    return bfbits2f(((const unsigned short*)p)[idx]);
}
__device__ __forceinline__ float4 loadbf4(const bf16* p) {
    ushort4 u = *reinterpret_cast<const ushort4*>(p);
    return make_float4(bfbits2f(u.x), bfbits2f(u.y), bfbits2f(u.z), bfbits2f(u.w));
}
__device__ __forceinline__ void store_bf4(bf16* p, float a, float b, float c, float d) {
    ushort4 o;
    o.x = f2bfbits(a); o.y = f2bfbits(b); o.z = f2bfbits(c); o.w = f2bfbits(d);
    *reinterpret_cast<ushort4*>(p) = o;
}
// async global->LDS, 16B per lane; LDS dest = wave-uniform base + lane*16
__device__ __forceinline__ void gl16(const void* g, void* l) {
    __builtin_amdgcn_global_load_lds(
        (const __attribute__((address_space(1))) unsigned int*)g,
        (__attribute__((address_space(3))) unsigned int*)l, 16, 0, 0);
}

// ---------- input dtype detection (flag=1: read raw inputs as fp32) -----------
__global__ __launch_bounds__(1024)
void detect_kernel(const unsigned short* __restrict__ x, int* __restrict__ flag) {
    const int tid = threadIdx.x;
    int zc = 0, hc = 0;
    const uint4* xv = (const uint4*)x;
#pragma unroll
    for (int p = 0; p < 16; ++p) {
        uint4 v = xv[p * 1024 + tid];
        unsigned s0 = v.x & 0xFFFFu, s1 = v.y & 0xFFFFu;
        unsigned s2 = v.z & 0xFFFFu, s3 = v.w & 0xFFFFu;
        zc += (int)(s0 == 0) + (int)(s1 == 0) + (int)(s2 == 0) + (int)(s3 == 0);
        hc += (int)(((s0 >> 7) & 0xFFu) >= 0x90u) + (int)(((s1 >> 7) & 0xFFu) >= 0x90u)
            + (int)(((s2 >> 7) & 0xFFu) >= 0x90u) + (int)(((s3 >> 7) & 0xFFu) >= 0x90u);
    }
#pragma unroll
    for (int off = 32; off > 0; off >>= 1) {
        zc += __shfl_down(zc, off);
        hc += __shfl_down(hc, off);
    }
    __shared__ int rz[16], rh[16];
    if ((tid & 63) == 0) { rz[tid >> 6] = zc; rh[tid >> 6] = hc; }
    __syncthreads();
    if (tid == 0) {
        int Z = 0, H = 0;
#pragma unroll
        for (int i = 0; i < 16; ++i) { Z += rz[i]; H += rh[i]; }
        *flag = (Z > 60000 || H > 256) ? 1 : 0;
    }
}

__global__ void diag_kernel(float* __restrict__ out, float val) {
    if (threadIdx.x == 0) out[0] = val;
}

// ---------- fused weight convert: all 6 weight tensors in one dispatch --------
__global__ __launch_bounds__(256)
void convert6_kernel(const void* __restrict__ s0, const void* __restrict__ s1,
                     const void* __restrict__ s2, const void* __restrict__ s3,
                     const void* __restrict__ s4, const void* __restrict__ s5,
                     bf16* __restrict__ dst, const int* __restrict__ dflag) {
    const bool f32 = (*dflag != 0);
    for (long i = (long)blockIdx.x * 256 + threadIdx.x; i < 4456448;
         i += (long)gridDim.x * 256) {
        const void* s; long o;
        if (i < 131072)       { s = s0; o = i; }
        else if (i < 196608)  { s = s1; o = i - 131072; }
        else if (i < 262144)  { s = s2; o = i - 196608; }
        else if (i < 2359296) { s = s3; o = i - 262144; }
        else if (i < 3407872) { s = s4; o = i - 2359296; }
        else                  { s = s5; o = i - 3407872; }
        dst[i] = __float2bfloat16(load1_any(s, o, f32));
    }
}

// ---------- transpose+convert: x[bg][256][1024] raw -> xT[z][1024][256] bf16 --
__global__ __launch_bounds__(256)
void xpose_conv_kernel(const void* __restrict__ x1, const void* __restrict__ x2,
                       bf16* __restrict__ dst, int bofs, int zsplit,
                       const int* __restrict__ dflag) {
    const bool f32 = (*dflag != 0);
    __shared__ float t[64][65];
    const int ch0 = blockIdx.y * 64, n0 = blockIdx.x * 64, z = blockIdx.z;
    const bool hiz = (z >= zsplit);
    const int zl = hiz ? z - zsplit : z;
    const void* x = hiz ? x2 : x1;
    const long sb = (long)(zl + bofs) * 262144, db = (long)z * 262144;
    const int tid = threadIdx.x;
#pragma unroll
    for (int p = 0; p < 16; ++p) {
        int e = tid + p * 256; int sch = e >> 6, sn = e & 63;
        t[sch][sn] = load1_any(x, sb + (long)(ch0 + sch) * 1024 + n0 + sn, f32);
    }
    __syncthreads();
#pragma unroll
    for (int p = 0; p < 16; ++p) {
        int e = tid + p * 256; int dn = e >> 6, dch = e & 63;
        dst[db + (long)(n0 + dn) * 256 + ch0 + dch] = __float2bfloat16(t[dch][dn]);
    }
}

// ---------- column softmax (no normalize), vectorized -------------------------
// X[z][1024][1024] bf16; softmax over rows j for each column n.
// X <- exp(X - colmax); invS[n] = 1/colsum.
// Block: 64 cols (8 groups x 8 cols, bf16x8 16B vectors) x 1024 rows
// (32 slices x 32 rows). Grid (16, nz) = 512 blocks, 2/CU.
__global__ __launch_bounds__(256)
void smnorm_kernel(bf16* __restrict__ X, float* __restrict__ invS) {
    const int tid = threadIdx.x;
    const int cg = tid & 7;            // col group (8 cols, 16B)
    const int js = tid >> 3;           // row slice (32 rows)
    const int n0 = blockIdx.x * 64;
    const long zb = (long)blockIdx.y * 1048576;
    unsigned short* Xp = (unsigned short*)X + zb + n0 + cg * 8;

    float m[8];
#pragma unroll
    for (int q = 0; q < 8; ++q) m[q] = -3.4e38f;
#pragma unroll 4
    for (int r = 0; r < 32; ++r) {
        bf16x8v u = *(const bf16x8v*)(Xp + (long)(js * 32 + r) * 1024);
#pragma unroll
        for (int q = 0; q < 8; ++q)
            m[q] = fmaxf(m[q], bfbits2f((unsigned short)u[q]));
    }
    __shared__ float sh[32][8][8];
    __shared__ float Mc[64];
#pragma unroll
    for (int q = 0; q < 8; ++q) sh[js][cg][q] = m[q];
    __syncthreads();
    if (tid < 64) {
        float mm = -3.4e38f;
#pragma unroll 8
        for (int s = 0; s < 32; ++s) mm = fmaxf(mm, sh[s][tid >> 3][tid & 7]);
        Mc[tid] = mm;
    }
    __syncthreads();
    float M8[8], s8[8];
#pragma unroll
    for (int q = 0; q < 8; ++q) { M8[q] = Mc[cg * 8 + q]; s8[q] = 0.f; }
#pragma unroll 4
    for (int r = 0; r < 32; ++r) {
        long off = (long)(js * 32 + r) * 1024;
        bf16x8v u = *(const bf16x8v*)(Xp + off);
        bf16x8v o;
#pragma unroll
        for (int q = 0; q < 8; ++q) {
            float e = __expf(bfbits2f((unsigned short)u[q]) - M8[q]);
            s8[q] += e;
            o[q] = (short)f2bfbits(e);
        }
        *(bf16x8v*)(Xp + off) = o;
    }
    __syncthreads();
#pragma unroll
    for (int q = 0; q < 8; ++q) sh[js][cg][q] = s8[q];
    __syncthreads();
    if (tid < 64) {
        float ss = 0.f;
#pragma unroll 8
        for (int s = 0; s < 32; ++s) ss += sh[s][tid >> 3][tid & 7];
        invS[(long)blockIdx.y * 1024 + n0 + tid] = 1.0f / ss;
    }
}

// ---------- unified NT MFMA GEMM, depth-5 pipeline, 1 barrier / K-step --------
// D[z][m][n] = sum_k A[z][m][k] * B[z][n][k]   (both operands k-contiguous)
// 128x128 tile / block (4 waves, each 64x64 via 4x4 grid of 16x16x32 MFMA).
// 5 LDS buffers; steady state keeps 3 stages (12 gl16) in flight:
//   vmcnt(12) -> barrier -> ds_read -> lgkmcnt(0) -> stage(t+4) -> MFMA
// Single barrier is safe: stage at t writes buf[(t+4)%5]=buf[(t-1)%5], whose
// readers (step t-1) retired their lgkmcnt(0) before reaching barrier(t);
// stage is issued after barrier(t); barrier skew <= 1 step.
// z-split: z<zsplit uses side-1 params, else side-2 (zl=z-zsplit); swapXY swaps
// the block-grid meaning for side-2 (merged dispatches with transposed shapes).
// EPI: 0 plain | 1 +bias[row] | 2 *scale+bias[row] | 3 +res fp32 out
//      4 (v+bias[row])*colscale[col]   (colscale = fp32 via res ptr, stride rBatch)
template <int EPI>
__global__ __launch_bounds__(256)
void mfma_nt(const bf16* __restrict__ A1, const bf16* __restrict__ A2,
             long aB1, long aB2, int ldA1, int ldA2,
             const bf16* __restrict__ B1, const bf16* __restrict__ B2,
             long bB1, long bB2, int ldB1, int ldB2,
             int ksplit, long kOff2,
             void* __restrict__ out1, void* __restrict__ out2,
             long oB1, long oB2, int ldO1, int ldO2,
             int K, float scale,
             const void* __restrict__ bias1, const void* __restrict__ bias2,
             const void* __restrict__ res1, const void* __restrict__ res2,
             long rBatch, int bofs, int zsplit, int swapXY,
             const int* __restrict__ dflag) {
    __shared__ short As[5][4096];   // [buf][128 rows x 32 shorts]  8KB each
    __shared__ short Bs[5][4096];
    const int tid  = threadIdx.x;
    const int lane = tid & 63, wave = tid >> 6;
    const int quad = lane >> 4, lrow = lane & 15;
    const int wm = (wave >> 1) * 64, wn = (wave & 1) * 64;
    const int z  = blockIdx.z;
    const bool hiz = (z >= zsplit);
    const int zl = hiz ? z - zsplit : z;
    const bool sw = hiz && swapXY;
    const int n0 = (sw ? blockIdx.y : blockIdx.x) * 128;
    const int m0 = (sw ? blockIdx.x : blockIdx.y) * 128;
    const int ldA = hiz ? ldA2 : ldA1, ldB = hiz ? ldB2 : ldB1;
    const int ldO = hiz ? ldO2 : ldO1;
    const int srow = tid >> 2, sseg = tid & 3;
    const int sl = sseg ^ ((srow >> 1) & 3);        // staging: swizzled logical seg
    const int xq = quad ^ ((lrow >> 1) & 3);        // read: physical seg for my quad

    const bf16* Ab = (hiz ? A2 : A1) + (long)zl * (hiz ? aB2 : aB1);
    const bf16* Bb = (hiz ? B2 : B1) + (long)zl * (hiz ? bB2 : bB1);

    auto stage = [&](int buf, int k0) {
        const bf16* asrc = Ab + (long)k0;
        const bf16* bsrc = Bb + ((k0 < ksplit) ? (long)k0 : (long)(k0 - ksplit) + kOff2);
        const bf16* ga0 = asrc + (long)(m0 + srow) * ldA + sl * 8;
        const bf16* ga1 = asrc + (long)(m0 + 64 + srow) * ldA + sl * 8;
        const bf16* gb0 = bsrc + (long)(n0 + srow) * ldB + sl * 8;
        const bf16* gb1 = bsrc + (long)(n0 + 64 + srow) * ldB + sl * 8;
        short* la = &As[buf][wave * 512];
        short* lb = &Bs[buf][wave * 512];
        gl16(ga0, la);
        gl16(ga1, la + 2048);
        gl16(gb0, lb);
        gl16(gb1, lb + 2048);
    };

    f32x4v acc[4][4] = {};
    const int nt = K >> 5;
    stage(0, 0);
    if (nt > 1) stage(1, 32);
    if (nt > 2) stage(2, 64);
    if (nt > 3) stage(3, 96);

    int cur = 0;
    for (int t = 0; t < nt; ++t) {
        const int rem = nt - 1 - t;
        if (rem >= 3)      asm volatile("s_waitcnt vmcnt(12)" ::: "memory");
        else if (rem == 2) asm volatile("s_waitcnt vmcnt(8)" ::: "memory");
        else if (rem == 1) asm volatile("s_waitcnt vmcnt(4)" ::: "memory");
        else               asm volatile("s_waitcnt vmcnt(0)" ::: "memory");
        __builtin_amdgcn_s_barrier();            // all waves' tile-t loads landed
        __builtin_amdgcn_sched_barrier(0);
        bf16x8v bfr[4], afr[4];
#pragma unroll
        for (int j = 0; j < 4; ++j)
            bfr[j] = *(const bf16x8v*)&Bs[cur][(wn + j * 16 + lrow) * 32 + xq * 8];
#pragma unroll
        for (int i = 0; i < 4; ++i)
            afr[i] = *(const bf16x8v*)&As[cur][(wm + i * 16 + lrow) * 32 + xq * 8];
        asm volatile("s_waitcnt lgkmcnt(0)" ::: "memory");
        __builtin_amdgcn_sched_barrier(0);       // rule 18: MFMA can't hoist above
        if (t + 4 < nt) {
            int nb = cur + 4; if (nb >= 5) nb -= 5;
            stage(nb, (t + 4) << 5);
        }
#pragma unroll
        for (int i = 0; i < 4; ++i)
#pragma unroll
            for (int j = 0; j < 4; ++j)
                acc[i][j] = __builtin_amdgcn_mfma_f32_16x16x32_bf16(afr[i], bfr[j], acc[i][j], 0, 0, 0);
        cur = (cur == 4) ? 0 : cur + 1;
    }

    const bool f32 = (*dflag != 0);
    const void* bias = hiz ? bias2 : bias1;
    if (EPI != 3) {
        bf16* O = (bf16*)(hiz ? out2 : out1) + (long)zl * (hiz ? oB2 : oB1);
        const float* csp = (EPI == 4)
            ? (const float*)(hiz ? res2 : res1) + (long)zl * rBatch : nullptr;
#pragma unroll
        for (int i = 0; i < 4; ++i) {
            int row0 = m0 + wm + i * 16 + quad * 4;
            float rb[4] = {0.f, 0.f, 0.f, 0.f};
            if (EPI == 1 || EPI == 2 || EPI == 4) {
#pragma unroll
                for (int r = 0; r < 4; ++r) rb[r] = load1_any(bias, row0 + r, f32);
            }
#pragma unroll
            for (int j = 0; j < 4; ++j) {
                int col = n0 + wn + j * 16 + lrow;
                float cs = (EPI == 4) ? csp[col] : 1.0f;
#pragma unroll
                for (int r = 0; r < 4; ++r) {
                    float vv = acc[i][j][r];
                    if (EPI == 1) vv += rb[r];
                    if (EPI == 2) vv = vv * scale + rb[r];
                    if (EPI == 4) vv = (vv + rb[r]) * cs;
                    O[(long)(row0 + r) * ldO + col] = __float2bfloat16(vv);
                }
            }
        }
    } else {
        float* O = (float*)(hiz ? out2 : out1);
        const void* res = hiz ? res2 : res1;
        const long ob  = (long)(zl + bofs) * (hiz ? oB2 : oB1);
        const long rbb = (long)(zl + bofs) * rBatch;
#pragma unroll
        for (int i = 0; i < 4; ++i) {
            int row0 = m0 + wm + i * 16 + quad * 4;
#pragma unroll
            for (int j = 0; j < 4; ++j) {
                int col = n0 + wn + j * 16 + lrow;
#pragma unroll
                for (int r = 0; r < 4; ++r) {
                    float rv = load1_any(res, rbb + (long)(row0 + r) * ldO + col, f32);
                    O[ob + (long)(row0 + r) * ldO + col] = acc[i][j][r] + rv;
                }
            }
        }
    }
}

// ---------- LayerNorm over last dim (1024), bf16 in-place ---------------------
__global__ __launch_bounds__(256)
void layernorm_kernel(bf16* __restrict__ x, const void* __restrict__ g,
                      const void* __restrict__ beta, const int* __restrict__ dflag) {
    const bool f32 = (*dflag != 0);
    bf16* p = x + (long)blockIdx.x * 1024;
    const int tid = threadIdx.x;
    float4 v = loadbf4(p + tid * 4);
    float s  = v.x + v.y + v.z + v.w;
    float ss = v.x * v.x + v.y * v.y + v.z * v.z + v.w * v.w;
#pragma unroll
    for (int off = 32; off > 0; off >>= 1) {
        s  += __shfl_down(s, off);
        ss += __shfl_down(ss, off);
    }
    __shared__ float sh[8];
    __shared__ float sh_mu, sh_rs;
    if ((tid & 63) == 0) { sh[tid >> 6] = s; sh[4 + (tid >> 6)] = ss; }
    __syncthreads();
    if (tid == 0) {
        float S  = sh[0] + sh[1] + sh[2] + sh[3];
        float SS = sh[4] + sh[5] + sh[6] + sh[7];
        float mu = S * (1.0f / 1024.0f);
        float var = SS * (1.0f / 1024.0f) - mu * mu;
        sh_mu = mu;
        sh_rs = rsqrtf(fmaxf(var, 0.0f) + 1e-5f);
    }
    __syncthreads();
    float mu = sh_mu, rs = sh_rs;
    float gx = load1_any(g, tid * 4 + 0, f32), gy = load1_any(g, tid * 4 + 1, f32);
    float gz = load1_any(g, tid * 4 + 2, f32), gw = load1_any(g, tid * 4 + 3, f32);
    float bx = load1_any(beta, tid * 4 + 0, f32), by = load1_any(beta, tid * 4 + 1, f32);
    float bz = load1_any(beta, tid * 4 + 2, f32), bw = load1_any(beta, tid * 4 + 3, f32);
    store_bf4(p + tid * 4,
              (v.x - mu) * rs * gx + bx, (v.y - mu) * rs * gy + by,
              (v.z - mu) * rs * gz + bz, (v.w - mu) * rs * gw + bw);
}

// ---------- host ---------------------------------------------------------------
extern "C" void kernel_launch(void* const* d_in, const int* in_sizes, int n_in,
                              void* d_out, int out_size, void* d_ws, size_t ws_size,
                              hipStream_t stream) {
    const void* x_spa  = d_in[0];
    const void* x_freq = d_in[1];
    const void* w_cdc  = d_in[2];
    const void* b_cdc  = d_in[3];
    const void* w_sv   = d_in[4];
    const void* b_sv   = d_in[5];
    const void* w_fv   = d_in[6];
    const void* b_fv   = d_in[7];
    const void* ln_w   = d_in[8];
    const void* ln_b   = d_in[9];
    const void* w_qk   = d_in[10];
    const void* w_spa  = d_in[11];
    const void* b_spa  = d_in[12];
    const void* w_frq  = d_in[13];
    const void* b_frq  = d_in[14];
    float* out = (float*)d_out;          // fp32 output

    const int B = 16, C = 256;
    const long XB = 262144;              // [256][1024] or [1024][256] tiles
    const long PB = 1048576;             // [1024][1024]

    // ws: 4KB header | bf16 weights (4,456,448 elems) | G * per-batch
    int*  dflag = (int*)d_ws;
    bf16* wb    = (bf16*)((char*)d_ws + 4096);
    bf16* w_cdc_b = wb;                       // 131072  (256 x 512)
    bf16* w_sv_b  = w_cdc_b + 131072;         // 65536   (256 x 256)
    bf16* w_fv_b  = w_sv_b  + 65536;          // 65536
    bf16* w_qk_b  = w_fv_b  + 65536;          // 2097152 (2048 x 1024)
    bf16* w_spa_b = w_qk_b  + 2097152;        // 1048576 (1024 x 1024)
    bf16* w_frq_b = w_spa_b + 1048576;        // 1048576
    bf16* pb      = w_frq_b + 1048576;

    const size_t fixedB = 4096 + 4456448ull * 2;
    const size_t perB   = 8921088ull;         // 9*XB*2 + 2*PB*2 + 2*1024*4 bytes
    size_t avail = (ws_size > fixedB) ? (ws_size - fixedB) : 0;
    long gmax = (long)(avail / perB);
    const bool wsOK = (gmax >= 1);
    int G = wsOK ? (int)(gmax > 16 ? 16 : gmax) : 1;

    bf16* xT    = pb;                     // [2z][1024][256]  (spa: z<g, frq: z>=g)
    bf16* xln   = xT   + 2L * G * XB;     // [z][256][1024]
    bf16* kb    = xln  + (long)G * XB;    // [z][256][1024]
    bf16* qT    = kb   + (long)G * XB;    // [z][1024][256]
    bf16* TT    = qT   + (long)G * XB;    // [2z][1024][256]
    bf16* vb    = TT   + 2L * G * XB;     // [2z][256][1024]
    bf16* attpT = vb   + 2L * G * XB;     // [2z][1024][1024]  scores^T -> E
    float* invS = (float*)(attpT + 2L * G * PB);  // [2z][1024]

    dim3 blk(256);
    detect_kernel<<<dim3(1), dim3(1024), 0, stream>>>((const unsigned short*)x_spa, dflag);

    if (!wsOK) {
        float mb = (float)(ws_size >> 20);
        diag_kernel<<<dim3(1), dim3(64), 0, stream>>>(out, 1000.0f * (mb + 1.0f));
        return;
    }

    // all weights -> bf16 in one dispatch
    convert6_kernel<<<dim3(4352), blk, 0, stream>>>(w_cdc, w_sv, w_fv, w_qk, w_spa, w_frq,
                                                    wb, dflag);

    for (int b0 = 0; b0 < B; b0 += G) {
        int g = (B - b0 < G) ? (B - b0) : G;

        // x_spa/x_freq -> xT[2g] (bf16, [n][ch])
        xpose_conv_kernel<<<dim3(16, 4, 2 * g), blk, 0, stream>>>(
            x_spa, x_freq, xT, b0, g, dflag);

        // xln = w_cdc @ cat(x_spa, x_freq)  (rowbias, K split at 256)
        mfma_nt<1><<<dim3(8, 2, g), blk, 0, stream>>>(
            w_cdc_b, w_cdc_b, 0, 0, 512, 512,
            xT, xT, XB, XB, 256, 256, 256, (long)g * XB,
            xln, xln, XB, XB, 1024, 1024,
            512, 1.0f, b_cdc, b_cdc, nullptr, nullptr, 0, 0, g, 0, dflag);
        layernorm_kernel<<<dim3(g * C), blk, 0, stream>>>(xln, ln_w, ln_b, dflag);

        // merged: lo z -> kb[c][m] = xln . w_qk_hi ; hi z -> qT[n][c] = w_qk_lo . xln
        mfma_nt<0><<<dim3(8, 2, 2 * g), blk, 0, stream>>>(
            xln, w_qk_b, XB, 0, 1024, 1024,
            w_qk_b + 1048576, xln, 0, XB, 1024, 1024, 1024, 0,
            kb, qT, XB, XB, 1024, 256,
            1024, 1.0f, nullptr, nullptr, nullptr, nullptr, 0, 0, g, 1, dflag);

        // TT (both): TT[z][j][c] = w_{spa,frq} @ k^T
        mfma_nt<0><<<dim3(2, 8, 2 * g), blk, 0, stream>>>(
            w_spa_b, w_frq_b, 0, 0, 1024, 1024,
            kb, kb, XB, XB, 1024, 1024, 1024, 0,
            TT, TT + (long)g * XB, XB, XB, 256, 256,
            1024, 1.0f, nullptr, nullptr, nullptr, nullptr, 0, 0, g, 0, dflag);

        // attp transposed (both): attpT[z][j][n] = scale * (TT[j].qT[n]) + bias[j]
        mfma_nt<2><<<dim3(8, 8, 2 * g), blk, 0, stream>>>(
            TT, TT + (long)g * XB, XB, XB, 256, 256,
            qT, qT, XB, XB, 256, 256, 256, 0,
            attpT, attpT + (long)g * PB, PB, PB, 1024, 1024,
            256, 0.03125f, b_spa, b_frq, nullptr, nullptr, 0, 0, g, 0, dflag);

        // column softmax: attpT <- exp(attpT - colmax), invS[n] = 1/colsum
        smnorm_kernel<<<dim3(16, 2 * g), blk, 0, stream>>>(attpT, invS);

        // v (both): vb[z][c][n] = (w_{s,f}v . x + b) * invS[n]
        mfma_nt<4><<<dim3(8, 2, 2 * g), blk, 0, stream>>>(
            w_sv_b, w_fv_b, 0, 0, 256, 256,
            xT, xT + (long)g * XB, XB, XB, 256, 256, 256, 0,
            vb, vb + (long)g * XB, XB, XB, 1024, 1024,
            256, 1.0f, b_sv, b_fv, invS, invS + (long)g * 1024, 1024, 0, g, 0, dflag);

        // out (both): out = v' @ E^T + x   (fp32 out)
        mfma_nt<3><<<dim3(8, 2, 2 * g), blk, 0, stream>>>(
            vb, vb + (long)g * XB, XB, XB, 1024, 1024,
            attpT, attpT + (long)g * PB, PB, PB, 1024, 1024, 1024, 0,
            out, out + 4194304, XB, XB, 1024, 1024,
            1024, 1.0f, nullptr, nullptr, x_spa, x_freq, XB, b0, g, 0, dflag);
    }
}